// Round 9
// baseline (657.157 us; speedup 1.0000x reference)
//
#include <hip/hip_runtime.h>

// LSTMDecoder: B=4096, LATENT=128, SEQ=512, HID=32, OUT=64. f32 in/out.
// Round 9: producer/consumer wave specialization.
//   Block = 768 threads = 12 waves (3/SIMD), grid = 256 (1 block/CU).
//   - Waves 0-7  (recurrence): jj=w&1, r_=w>>1. Per step: 4 gate MFMAs
//     (sigma-permuted transposed recurrence, tiles {jj,2+jj,4+jj,6+jj}),
//     activation for ONE cell/lane (cell 4kb+16jj+r_, row n_), ds_write_b16,
//     barrier, 2x ds_read_b64 -> next fragment. No stores, no divergence.
//   - Waves 8-11 (projection): after the same barrier, read the fresh
//     fragment, 1 MFMA (y^T tile p=w-8), 1 global_store_dwordx4. Their
//     store/vmcnt latency is OFF the recurrence critical path (a full step
//     of slack; barrier arrival early next iter).
//   - Exchange buffer 4-deep (hx[t&3]): proj waves read buf u during
//     interval t; writers reuse it at t+4, fenced by 3 barriers => race-free
//     with a single lgkm-only barrier per step (no vmcnt drain).
//   - State: c fp32 (1/lane on rec waves); h carried f16 RNE (verified:
//     absmax stays at the output bf16 quantum).

#define B_SZ   4096
#define LATENT 128
#define SEQ    512
#define HID    32
#define OUT_N  64
#define ROWS   16
#define LSW    40   // h0 staging row stride in halves (80 B rows)

typedef _Float16 f16x8 __attribute__((ext_vector_type(8)));
typedef _Float16 f16x4 __attribute__((ext_vector_type(4)));
typedef float    f32x4 __attribute__((ext_vector_type(4)));

__device__ __forceinline__ float fexp2(float x) { return __builtin_amdgcn_exp2f(x); }
__device__ __forceinline__ float frcp(float x)  { return __builtin_amdgcn_rcpf(x); }
__device__ __forceinline__ float sigm(float x) {
    return frcp(1.f + fexp2(-1.44269504088896341f * x));
}
__device__ __forceinline__ float tanh_f(float x) {
    return fmaf(-2.f, frcp(1.f + fexp2(2.88539008177792681f * x)), 1.f);
}
__device__ __forceinline__ void lds_barrier() {
    asm volatile("s_waitcnt lgkmcnt(0)\n\ts_barrier" ::: "memory");
}

__global__ __launch_bounds__(768)
void lstm_pc(const float* __restrict__ z,
             const float* __restrict__ init_W,
             const float* __restrict__ init_b,
             const float* __restrict__ W_hh,
             const float* __restrict__ b_ih,
             const float* __restrict__ b_hh,
             const float* __restrict__ out_W,
             const float* __restrict__ out_b,
             float* __restrict__ y)
{
    __shared__ __align__(16) _Float16 hst[ROWS * LSW];
    __shared__ __align__(8) unsigned short hx[4][2][64][4];  // [t&3][jj][lane][r]

    const int tid  = threadIdx.x;
    const int w    = tid >> 6;          // wave 0..11
    const int lane = tid & 63;
    const int n_   = lane & 15;         // batch row within tile
    const int kb   = lane >> 4;         // k-group / D row-group
    const bool rec = (w < 8);
    const int jj   = w & 1;             // (rec) cell half
    const int r_   = (w >> 1) & 3;      // (rec) D reg / (proj) unused
    const int p_   = w - 8;             // (proj) output tile
    const int rbase = blockIdx.x * ROWS;

    // ---- per-role resident fragments ----
    f16x8 wf[4];     // rec: W_hh tiles {jj,2+jj,4+jj,6+jj}; proj: only wf[0]=out_W tile
    f32x4 bacc[4];   // rec: gate biases; proj: only bacc[0]=out biases
    if (rec) {
#pragma unroll
        for (int m = 0; m < 4; m++) {
            int g = 2 * m + jj;
            const float* row = W_hh + (size_t)(16 * g + n_) * HID;
            f16x8 v;
#pragma unroll
            for (int rr = 0; rr < 4; rr++) {
                v[rr]     = (_Float16)row[4 * kb + rr];
                v[4 + rr] = (_Float16)row[4 * kb + 16 + rr];
            }
            wf[m] = v;
            f32x4 b;
#pragma unroll
            for (int r = 0; r < 4; r++) {
                int G = 16 * g + 4 * kb + r;
                b[r] = b_ih[G] + b_hh[G];
            }
            bacc[m] = b;
        }
    } else {
        const float* row = out_W + (size_t)(16 * p_ + n_) * HID;
        f16x8 v;
#pragma unroll
        for (int rr = 0; rr < 4; rr++) {
            v[rr]     = (_Float16)row[4 * kb + rr];
            v[4 + rr] = (_Float16)row[4 * kb + 16 + rr];
        }
        wf[0] = v;
        f32x4 b;
#pragma unroll
        for (int r = 0; r < 4; r++) b[r] = out_b[16 * p_ + 4 * kb + r];
        bacc[0] = b;
    }

    // ---- h0 = z @ init_W^T + init_b (threads 0..511: one cell each) ----
    if (tid < 512) {
        int m = tid >> 5, j = tid & 31;
        const float4* zp = (const float4*)(z + (size_t)(rbase + m) * LATENT);
        const float4* wp = (const float4*)(init_W + (size_t)j * LATENT);
        float acc = init_b[j];
#pragma unroll
        for (int k = 0; k < LATENT / 4; k++) {
            float4 a4 = zp[k], b4 = wp[k];
            acc = fmaf(a4.x, b4.x, acc); acc = fmaf(a4.y, b4.y, acc);
            acc = fmaf(a4.z, b4.z, acc); acc = fmaf(a4.w, b4.w, acc);
        }
        hst[m * LSW + j] = (_Float16)acc;
    }
    __syncthreads();

    // rec: initial fragment slot 4jj'+rr <- h0[n_][4kb+16jj'+rr]
    f16x8 a;
    if (rec) {
        f16x4 lo = *(const f16x4*)&hst[n_ * LSW + 4 * kb];
        f16x4 hi = *(const f16x4*)&hst[n_ * LSW + 4 * kb + 16];
#pragma unroll
        for (int r = 0; r < 4; r++) { a[r] = lo[r]; a[4 + r] = hi[r]; }
    }

    float c1 = 0.f;  // rec: cell 4kb+16jj+r_, row n_

    float* yb = y + (size_t)(rbase + n_) * SEQ * OUT_N + 16 * p_ + 4 * kb;

    for (int t = 0; t < SEQ; t += 4) {
#pragma unroll
        for (int u = 0; u < 4; u++) {
            if (rec) {
                // gates: issue f first (cn needs it), o last (needed last)
                f32x4 af = __builtin_amdgcn_mfma_f32_16x16x32_f16(wf[1], a, bacc[1], 0, 0, 0);
                f32x4 ai = __builtin_amdgcn_mfma_f32_16x16x32_f16(wf[0], a, bacc[0], 0, 0, 0);
                f32x4 ag = __builtin_amdgcn_mfma_f32_16x16x32_f16(wf[2], a, bacc[2], 0, 0, 0);
                f32x4 ao = __builtin_amdgcn_mfma_f32_16x16x32_f16(wf[3], a, bacc[3], 0, 0, 0);
                float gf = sigm(af[r_]);
                float gi = sigm(ai[r_]);
                float gg = tanh_f(ag[r_]);
                float cn = fmaf(gf, c1, gi * gg);
                c1 = cn;
                float go = sigm(ao[r_]);
                union { _Float16 h; unsigned short u16; } cv;
                cv.h = (_Float16)(go * tanh_f(cn));
                hx[u][jj][lane][r_] = cv.u16;
            }
            lds_barrier();
            // everyone: gather the fresh fragment (2-way bank class = free)
            f16x4 lo = *(const f16x4*)&hx[u][0][lane][0];
            f16x4 hi = *(const f16x4*)&hx[u][1][lane][0];
            if (rec) {
#pragma unroll
                for (int r = 0; r < 4; r++) { a[r] = lo[r]; a[4 + r] = hi[r]; }
            } else {
                f16x8 ap;
#pragma unroll
                for (int r = 0; r < 4; r++) { ap[r] = lo[r]; ap[4 + r] = hi[r]; }
                f32x4 py = __builtin_amdgcn_mfma_f32_16x16x32_f16(wf[0], ap, bacc[0], 0, 0, 0);
                *(f32x4*)(yb + (size_t)(t + u) * OUT_N) = py;
            }
        }
    }
}

extern "C" void kernel_launch(void* const* d_in, const int* in_sizes, int n_in,
                              void* d_out, int out_size, void* d_ws, size_t ws_size,
                              hipStream_t stream) {
    const float* z      = (const float*)d_in[0];
    const float* init_W = (const float*)d_in[1];
    const float* init_b = (const float*)d_in[2];
    // d_in[3] = W_ih: unused (x input is all zeros; only biases survive)
    const float* W_hh   = (const float*)d_in[4];
    const float* b_ih   = (const float*)d_in[5];
    const float* b_hh   = (const float*)d_in[6];
    const float* out_W  = (const float*)d_in[7];
    const float* out_b  = (const float*)d_in[8];
    float* yout = (float*)d_out;

    lstm_pc<<<B_SZ / ROWS, 768, 0, stream>>>(z, init_W, init_b, W_hh, b_ih, b_hh,
                                             out_W, out_b, yout);
}